// Round 1
// baseline (78.622 us; speedup 1.0000x reference)
//
#include <hip/hip_runtime.h>
#include <stdint.h>

#define N_NODES 100000
#define DEG 16
#define IN_F 128
#define OUT_F 64
#define ALPHA 0.2f

typedef __attribute__((ext_vector_type(8))) short short8;
typedef __attribute__((ext_vector_type(4))) float f32x4;
typedef __attribute__((ext_vector_type(4))) int i32x4;

static __device__ __forceinline__ short f2bf(float f) {
    // round-to-nearest-even f32 -> bf16 (finite inputs only)
    uint32_t u = __float_as_uint(f);
    u += 0x7FFFu + ((u >> 16) & 1u);
    return (short)(u >> 16);
}
static __device__ __forceinline__ float bf2f(unsigned short u) {
    return __uint_as_float(((uint32_t)u) << 16);
}

// Kernel 1: feat = x @ w^T (bf16 MFMA, f32 accum), a1 = feat@a1w+b, a2 = feat@a2w+b.
// One wave = 16 nodes x 64 features. feat stored as bf16 for the gather kernel.
__global__ __launch_bounds__(256) void gat_feat_kernel(
    const float* __restrict__ x, const float* __restrict__ w,
    const float* __restrict__ a1w, const float* __restrict__ a1bp,
    const float* __restrict__ a2w, const float* __restrict__ a2bp,
    unsigned short* __restrict__ featb, float* __restrict__ a1,
    float* __restrict__ a2)
{
    __shared__ __align__(16) unsigned short lds[4][16][64]; // per-wave store-bounce tile, 8 KB
    const int wid  = threadIdx.x >> 6;
    const int lane = threadIdx.x & 63;
    const int r = lane & 15;   // A row / B col within 16-tile
    const int g = lane >> 4;   // k-group (8 contiguous k per group)
    const int base = (blockIdx.x * 4 + wid) * 16;
    if (base >= N_NODES) return;

    // B fragments: B[k][n] = w[n][k]; lane holds w[ft*16+r][ks*32+g*8 .. +7]
    short8 bfrag[4][4];
    #pragma unroll
    for (int ft = 0; ft < 4; ++ft) {
        #pragma unroll
        for (int ks = 0; ks < 4; ++ks) {
            const float* wp = w + (ft * 16 + r) * IN_F + ks * 32 + g * 8;
            f32x4 w0 = *(const f32x4*)(wp);
            f32x4 w1 = *(const f32x4*)(wp + 4);
            short8 t;
            t[0] = f2bf(w0[0]); t[1] = f2bf(w0[1]);
            t[2] = f2bf(w0[2]); t[3] = f2bf(w0[3]);
            t[4] = f2bf(w1[0]); t[5] = f2bf(w1[1]);
            t[6] = f2bf(w1[2]); t[7] = f2bf(w1[3]);
            bfrag[ft][ks] = t;
        }
    }

    f32x4 acc[4];
    #pragma unroll
    for (int ft = 0; ft < 4; ++ft) acc[ft] = (f32x4){0.f, 0.f, 0.f, 0.f};

    const float* xrow = x + (size_t)(base + r) * IN_F;
    #pragma unroll
    for (int ks = 0; ks < 4; ++ks) {
        const float* xp = xrow + ks * 32 + g * 8;
        f32x4 x0 = *(const f32x4*)(xp);
        f32x4 x1 = *(const f32x4*)(xp + 4);
        short8 af;
        af[0] = f2bf(x0[0]); af[1] = f2bf(x0[1]);
        af[2] = f2bf(x0[2]); af[3] = f2bf(x0[3]);
        af[4] = f2bf(x1[0]); af[5] = f2bf(x1[1]);
        af[6] = f2bf(x1[2]); af[7] = f2bf(x1[3]);
        #pragma unroll
        for (int ft = 0; ft < 4; ++ft)
            acc[ft] = __builtin_amdgcn_mfma_f32_16x16x32_bf16(af, bfrag[ft][ks], acc[ft], 0, 0, 0);
    }
    // C/D layout (HW-verified): col = lane&15 -> feature ft*16+r; row = g*4+reg -> node base+g*4+reg

    // a1/a2 from f32 accumulators (keeps exp() inputs full precision)
    float p1[4] = {0.f,0.f,0.f,0.f}, p2[4] = {0.f,0.f,0.f,0.f};
    #pragma unroll
    for (int ft = 0; ft < 4; ++ft) {
        float w1v = a1w[ft * 16 + r];
        float w2v = a2w[ft * 16 + r];
        #pragma unroll
        for (int reg = 0; reg < 4; ++reg) {
            p1[reg] += acc[ft][reg] * w1v;
            p2[reg] += acc[ft][reg] * w2v;
        }
    }
    #pragma unroll
    for (int m = 1; m <= 8; m <<= 1) {
        #pragma unroll
        for (int reg = 0; reg < 4; ++reg) {
            p1[reg] += __shfl_xor(p1[reg], m, 64);
            p2[reg] += __shfl_xor(p2[reg], m, 64);
        }
    }
    if (r == 0) {
        float b1 = a1bp[0], b2 = a2bp[0];
        #pragma unroll
        for (int reg = 0; reg < 4; ++reg) {
            a1[base + g * 4 + reg] = p1[reg] + b1;
            a2[base + g * 4 + reg] = p2[reg] + b2;
        }
    }

    // feat -> bf16, bounce through LDS so the global store is fully coalesced
    #pragma unroll
    for (int ft = 0; ft < 4; ++ft) {
        #pragma unroll
        for (int reg = 0; reg < 4; ++reg) {
            lds[wid][g * 4 + reg][ft * 16 + r] = (unsigned short)f2bf(acc[ft][reg]);
        }
    }
    // same-wave LDS RAW: compiler inserts lgkmcnt wait; tile is wave-private (no barrier)
    const char* lsrc = (const char*)(&lds[wid][0][0]);
    i32x4 d0 = *(const i32x4*)(lsrc + lane * 32);
    i32x4 d1 = *(const i32x4*)(lsrc + lane * 32 + 16);
    char* gdst = (char*)featb + (size_t)base * (OUT_F * 2);
    *(i32x4*)(gdst + lane * 32) = d0;
    *(i32x4*)(gdst + lane * 32 + 16) = d1;
}

// Kernel 2: per-node scores + gather-aggregate. One wave per node (src-sorted, 16 edges/node).
// lane = output feature; lanes' (lane&15) slot computes that edge's score redundantly x4.
__global__ __launch_bounds__(256) void gat_agg_kernel(
    const int* __restrict__ dst, const unsigned short* __restrict__ featb,
    const float* __restrict__ a1, const float* __restrict__ a2,
    const float* __restrict__ bias, float* __restrict__ out)
{
    const int wid  = threadIdx.x >> 6;
    const int lane = threadIdx.x & 63;
    const int i = blockIdx.x * 4 + wid;
    if (i >= N_NODES) return;

    int d = dst[i * DEG + (lane & 15)];
    float z = a1[i] + a2[d];
    float s = expf(z >= 0.f ? z : ALPHA * z);
    float ssum = s;
    #pragma unroll
    for (int m = 1; m <= 8; m <<= 1) ssum += __shfl_xor(ssum, m, 64);
    // every lane now holds sum of the 16 edge scores

    float acc = 0.f;
    #pragma unroll
    for (int e = 0; e < DEG; ++e) {
        int   de = __shfl(d, e, 64);
        float se = __shfl(s, e, 64);
        acc += se * bf2f(featb[(size_t)de * OUT_F + lane]); // one 128B line per edge
    }
    out[(size_t)i * OUT_F + lane] = acc / ssum + bias[lane];
}

extern "C" void kernel_launch(void* const* d_in, const int* in_sizes, int n_in,
                              void* d_out, int out_size, void* d_ws, size_t ws_size,
                              hipStream_t stream) {
    (void)in_sizes; (void)n_in; (void)out_size; (void)ws_size;
    const float* x    = (const float*)d_in[0];
    const int*   edges= (const int*)d_in[1];   // [2, E] int32, row0=src, row1=dst
    const float* w    = (const float*)d_in[2];
    const float* a1w  = (const float*)d_in[3];
    const float* a1b  = (const float*)d_in[4];
    const float* a2w  = (const float*)d_in[5];
    const float* a2b  = (const float*)d_in[6];
    const float* bias = (const float*)d_in[7];
    float* out = (float*)d_out;

    unsigned short* featb = (unsigned short*)d_ws;                      // N*64 bf16 = 12.8 MB
    float* a1 = (float*)((char*)d_ws + (size_t)N_NODES * OUT_F * 2);    // N f32
    float* a2 = a1 + N_NODES;                                           // N f32

    const int* dst = edges + (size_t)N_NODES * DEG; // edges[1]

    gat_feat_kernel<<<dim3((N_NODES + 63) / 64), dim3(256), 0, stream>>>(
        x, w, a1w, a1b, a2w, a2b, featb, a1, a2);
    gat_agg_kernel<<<dim3((N_NODES + 3) / 4), dim3(256), 0, stream>>>(
        dst, featb, a1, a2, bias, out);
}

// Round 2
// 58.099 us; speedup vs baseline: 1.3532x; 1.3532x over previous
//
#include <hip/hip_runtime.h>
#include <stdint.h>

#define N_NODES 100000
#define DEG 16
#define IN_F 128
#define OUT_F 64
#define ALPHA 0.2f

typedef __attribute__((ext_vector_type(8))) short short8;
typedef __attribute__((ext_vector_type(4))) float f32x4;
typedef __attribute__((ext_vector_type(4))) int i32x4;
typedef __attribute__((ext_vector_type(2))) unsigned int u32x2;

static __device__ __forceinline__ short f2bf(float f) {
    // round-to-nearest-even f32 -> bf16 (finite inputs only)
    uint32_t u = __float_as_uint(f);
    u += 0x7FFFu + ((u >> 16) & 1u);
    return (short)(u >> 16);
}

// Tiny kernel: convert w [64][128] f32 -> bf16 once per launch (8192 elems).
// Destination is the first 16 KB of d_out, which gat_agg fully overwrites later.
__global__ __launch_bounds__(256) void w_conv_kernel(const float* __restrict__ w,
                                                     unsigned short* __restrict__ wb) {
    int idx = blockIdx.x * 256 + threadIdx.x;
    if (idx < OUT_F * IN_F) wb[idx] = (unsigned short)f2bf(w[idx]);
}

// Kernel 1: feat = x @ w^T via bf16 MFMA (f32 accum), a1/a2 from f32 accumulators.
// One wave = 32 nodes (MT=2 row-tiles of 16) x 64 features; w fragments loaded as bf16
// (pre-converted), reused across both row-tiles.
__global__ __launch_bounds__(256) void gat_feat_kernel(
    const float* __restrict__ x, const unsigned short* __restrict__ wb,
    const float* __restrict__ a1w, const float* __restrict__ a1bp,
    const float* __restrict__ a2w, const float* __restrict__ a2bp,
    unsigned short* __restrict__ featb, float* __restrict__ a1,
    float* __restrict__ a2)
{
    __shared__ __align__(16) unsigned short lds[4][32][64]; // per-wave store-bounce tile, 16 KB
    const int wid  = threadIdx.x >> 6;
    const int lane = threadIdx.x & 63;
    const int r = lane & 15;   // A row / B col within 16-tile
    const int g = lane >> 4;   // k-group (8 contiguous k per group)
    const int base = (blockIdx.x * 4 + wid) * 32;
    if (base >= N_NODES) return;   // N % 32 == 0: active waves are always full

    // B fragments (bf16, no conversion): lane holds w[ft*16+r][ks*32+g*8 .. +7]
    short8 bfrag[4][4];
    #pragma unroll
    for (int ft = 0; ft < 4; ++ft)
        #pragma unroll
        for (int ks = 0; ks < 4; ++ks)
            bfrag[ft][ks] = *(const short8*)(wb + (ft * 16 + r) * IN_F + ks * 32 + g * 8);

    f32x4 acc[2][4];
    #pragma unroll
    for (int mt = 0; mt < 2; ++mt)
        #pragma unroll
        for (int ft = 0; ft < 4; ++ft) acc[mt][ft] = (f32x4){0.f, 0.f, 0.f, 0.f};

    #pragma unroll
    for (int mt = 0; mt < 2; ++mt) {
        const float* xrow = x + (size_t)(base + mt * 16 + r) * IN_F;
        #pragma unroll
        for (int ks = 0; ks < 4; ++ks) {
            const float* xp = xrow + ks * 32 + g * 8;
            f32x4 x0 = *(const f32x4*)(xp);
            f32x4 x1 = *(const f32x4*)(xp + 4);
            short8 af;
            af[0] = f2bf(x0[0]); af[1] = f2bf(x0[1]);
            af[2] = f2bf(x0[2]); af[3] = f2bf(x0[3]);
            af[4] = f2bf(x1[0]); af[5] = f2bf(x1[1]);
            af[6] = f2bf(x1[2]); af[7] = f2bf(x1[3]);
            #pragma unroll
            for (int ft = 0; ft < 4; ++ft)
                acc[mt][ft] = __builtin_amdgcn_mfma_f32_16x16x32_bf16(af, bfrag[ft][ks], acc[mt][ft], 0, 0, 0);
        }
    }
    // C/D layout (HW-verified): col = lane&15 -> feature ft*16+r; row = g*4+reg -> node mt*16+g*4+reg

    // a1/a2 from f32 accumulators (keeps exp() inputs full precision)
    float w1v[4], w2v[4];
    #pragma unroll
    for (int ft = 0; ft < 4; ++ft) { w1v[ft] = a1w[ft * 16 + r]; w2v[ft] = a2w[ft * 16 + r]; }
    float p1[2][4] = {{0.f,0.f,0.f,0.f},{0.f,0.f,0.f,0.f}};
    float p2[2][4] = {{0.f,0.f,0.f,0.f},{0.f,0.f,0.f,0.f}};
    #pragma unroll
    for (int mt = 0; mt < 2; ++mt)
        #pragma unroll
        for (int ft = 0; ft < 4; ++ft)
            #pragma unroll
            for (int reg = 0; reg < 4; ++reg) {
                p1[mt][reg] += acc[mt][ft][reg] * w1v[ft];
                p2[mt][reg] += acc[mt][ft][reg] * w2v[ft];
            }
    #pragma unroll
    for (int m = 1; m <= 8; m <<= 1)
        #pragma unroll
        for (int mt = 0; mt < 2; ++mt)
            #pragma unroll
            for (int reg = 0; reg < 4; ++reg) {
                p1[mt][reg] += __shfl_xor(p1[mt][reg], m, 64);
                p2[mt][reg] += __shfl_xor(p2[mt][reg], m, 64);
            }
    if (r == 0) {
        float b1 = a1bp[0], b2 = a2bp[0];
        #pragma unroll
        for (int mt = 0; mt < 2; ++mt)
            #pragma unroll
            for (int reg = 0; reg < 4; ++reg) {
                a1[base + mt * 16 + g * 4 + reg] = p1[mt][reg] + b1;
                a2[base + mt * 16 + g * 4 + reg] = p2[mt][reg] + b2;
            }
    }

    // feat -> bf16, bounce through LDS so the global store is fully coalesced
    #pragma unroll
    for (int mt = 0; mt < 2; ++mt)
        #pragma unroll
        for (int ft = 0; ft < 4; ++ft)
            #pragma unroll
            for (int reg = 0; reg < 4; ++reg)
                lds[wid][mt * 16 + g * 4 + reg][ft * 16 + r] = (unsigned short)f2bf(acc[mt][ft][reg]);
    // same-wave LDS RAW: compiler inserts lgkmcnt wait; tile is wave-private (no barrier)
    const char* lsrc = (const char*)(&lds[wid][0][0]);
    char* gdst = (char*)featb + (size_t)base * (OUT_F * 2);
    #pragma unroll
    for (int t = 0; t < 4; ++t) {
        i32x4 v = *(const i32x4*)(lsrc + t * 1024 + lane * 16);
        *(i32x4*)(gdst + t * 1024 + lane * 16) = v;
    }
}

// Kernel 2: per-node scores + gather-aggregate. One wave = 4 nodes (src-sorted, 16
// edges/node); lane = (node-slot q = lane>>4, feature-quad e0 = lane&15). Each gather
// is a dwordx2 (4 bf16 features); 16 lanes cover the full 128 B feat row.
__global__ __launch_bounds__(256) void gat_agg_kernel(
    const int* __restrict__ dst, const unsigned short* __restrict__ featb,
    const float* __restrict__ a1, const float* __restrict__ a2,
    const float* __restrict__ bias, float* __restrict__ out)
{
    const int wid  = threadIdx.x >> 6;
    const int lane = threadIdx.x & 63;
    const int q  = lane >> 4;      // node slot within wave
    const int e0 = lane & 15;      // edge slot (for scores) / feature-quad (for gather)
    const int i = (blockIdx.x * 4 + wid) * 4 + q;   // N % 16 == 0: grid exact

    const int d = dst[i * DEG + e0];
    const float z = a1[i] + a2[d];
    const float s = __expf(z >= 0.f ? z : ALPHA * z);
    float ssum = s;
    #pragma unroll
    for (int m = 1; m <= 8; m <<= 1) ssum += __shfl_xor(ssum, m, 64); // within 16-lane group
    const float inv = 1.0f / ssum;

    float acc0 = 0.f, acc1 = 0.f, acc2 = 0.f, acc3 = 0.f;
    const int srcbase = lane & 48;  // first lane of this node's 16-lane group
    #pragma unroll
    for (int e = 0; e < DEG; ++e) {
        const int   de = __shfl(d, srcbase + e, 64);
        const float se = __shfl(s, srcbase + e, 64);
        u32x2 u = *(const u32x2*)(featb + (size_t)(de * OUT_F + e0 * 4));
        acc0 += se * __uint_as_float(u[0] << 16);
        acc1 += se * __uint_as_float(u[0] & 0xffff0000u);
        acc2 += se * __uint_as_float(u[1] << 16);
        acc3 += se * __uint_as_float(u[1] & 0xffff0000u);
    }
    const f32x4 bv = *(const f32x4*)(bias + e0 * 4);
    f32x4 o;
    o[0] = acc0 * inv + bv[0];
    o[1] = acc1 * inv + bv[1];
    o[2] = acc2 * inv + bv[2];
    o[3] = acc3 * inv + bv[3];
    *(f32x4*)(out + (size_t)i * OUT_F + e0 * 4) = o;
}

extern "C" void kernel_launch(void* const* d_in, const int* in_sizes, int n_in,
                              void* d_out, int out_size, void* d_ws, size_t ws_size,
                              hipStream_t stream) {
    (void)in_sizes; (void)n_in; (void)out_size; (void)ws_size;
    const float* x    = (const float*)d_in[0];
    const int*   edges= (const int*)d_in[1];   // [2, E] int32, row0=src, row1=dst
    const float* w    = (const float*)d_in[2];
    const float* a1w  = (const float*)d_in[3];
    const float* a1b  = (const float*)d_in[4];
    const float* a2w  = (const float*)d_in[5];
    const float* a2b  = (const float*)d_in[6];
    const float* bias = (const float*)d_in[7];
    float* out = (float*)d_out;

    unsigned short* featb = (unsigned short*)d_ws;                      // N*64 bf16 = 12.8 MB
    float* a1 = (float*)((char*)d_ws + (size_t)N_NODES * OUT_F * 2);    // N f32
    float* a2 = a1 + N_NODES;                                           // N f32
    // bf16 copy of w lives in the first 16 KB of d_out: read only by gat_feat_kernel,
    // then fully overwritten by gat_agg_kernel's output writes. Deterministic per call.
    unsigned short* wb = (unsigned short*)d_out;

    const int* dst = edges + (size_t)N_NODES * DEG; // edges[1]

    w_conv_kernel<<<dim3((OUT_F * IN_F + 255) / 256), dim3(256), 0, stream>>>(w, wb);
    gat_feat_kernel<<<dim3((N_NODES + 127) / 128), dim3(256), 0, stream>>>(
        x, wb, a1w, a1b, a2w, a2b, featb, a1, a2);
    gat_agg_kernel<<<dim3((N_NODES + 15) / 16), dim3(256), 0, stream>>>(
        dst, featb, a1, a2, bias, out);
}

// Round 3
// 57.827 us; speedup vs baseline: 1.3596x; 1.0047x over previous
//
#include <hip/hip_runtime.h>
#include <stdint.h>

#define N_NODES 100000
#define DEG 16
#define IN_F 128
#define OUT_F 64
#define ALPHA 0.2f

typedef __attribute__((ext_vector_type(8))) short short8;
typedef __attribute__((ext_vector_type(4))) float f32x4;
typedef __attribute__((ext_vector_type(4))) int i32x4;
typedef __attribute__((ext_vector_type(2))) unsigned int u32x2;

static __device__ __forceinline__ unsigned short f2bf(float f) {
    // round-to-nearest-even f32 -> bf16 (finite inputs only)
    uint32_t u = __float_as_uint(f);
    u += 0x7FFFu + ((u >> 16) & 1u);
    return (unsigned short)(u >> 16);
}

// Prep: w -> bf16 (all blocks), v1 = w^T a1w, v2 = w^T a2w (block 0).
// a1 = feat@a1w = x@(w^T a1w) = x@v1  -- exact algebraic refactor, f32 throughout.
__global__ __launch_bounds__(256) void prep_kernel(
    const float* __restrict__ w, const float* __restrict__ a1w,
    const float* __restrict__ a2w, unsigned short* __restrict__ wb,
    float* __restrict__ v1, float* __restrict__ v2)
{
    int idx = blockIdx.x * 256 + threadIdx.x;
    if (idx < OUT_F * IN_F) wb[idx] = f2bf(w[idx]);
    if (blockIdx.x == 0) {
        int t = threadIdx.x;
        int k = t & (IN_F - 1);
        const float* aw = (t < IN_F) ? a1w : a2w;
        float acc = 0.f;
        #pragma unroll
        for (int f = 0; f < OUT_F; ++f) acc += w[f * IN_F + k] * aw[f];
        if (t < IN_F) v1[k] = acc; else v2[k] = acc;
    }
}

// Kernel 1: feat = x @ w^T via bf16 MFMA (f32 accum); a1/a2 via f32 dots x.v1, x.v2.
// One wave = 32 nodes (2 row-tiles of 16) x 64 features. w fragments re-read per ks
// (L1-resident) to keep VGPR low -> 4 waves/SIMD.
__global__ __launch_bounds__(256) void gat_feat_kernel(
    const float* __restrict__ x, const unsigned short* __restrict__ wb,
    const float* __restrict__ v1, const float* __restrict__ v2,
    const float* __restrict__ a1bp, const float* __restrict__ a2bp,
    unsigned short* __restrict__ featb, float* __restrict__ a1,
    float* __restrict__ a2)
{
    __shared__ __align__(16) unsigned short lds[4][32][64]; // per-wave store-bounce tile
    const int wid  = threadIdx.x >> 6;
    const int lane = threadIdx.x & 63;
    const int r = lane & 15;   // A row / B col within 16-tile
    const int g = lane >> 4;   // k-group (8 contiguous k per group)
    const int base = (blockIdx.x * 4 + wid) * 32;
    if (base >= N_NODES) return;   // N % 32 == 0: active waves always full

    f32x4 acc[2][4];
    #pragma unroll
    for (int mt = 0; mt < 2; ++mt)
        #pragma unroll
        for (int ft = 0; ft < 4; ++ft) acc[mt][ft] = (f32x4){0.f, 0.f, 0.f, 0.f};
    float p1[2] = {0.f, 0.f}, p2[2] = {0.f, 0.f};

    #pragma unroll
    for (int ks = 0; ks < 4; ++ks) {
        // B fragments for this ks (bf16, pre-converted; L1-hot across waves)
        short8 bf[4];
        #pragma unroll
        for (int ft = 0; ft < 4; ++ft)
            bf[ft] = *(const short8*)(wb + (ft * 16 + r) * IN_F + ks * 32 + g * 8);
        const float* vp1 = v1 + ks * 32 + g * 8;
        const float* vp2 = v2 + ks * 32 + g * 8;
        f32x4 v10 = *(const f32x4*)(vp1),     v11 = *(const f32x4*)(vp1 + 4);
        f32x4 v20 = *(const f32x4*)(vp2),     v21 = *(const f32x4*)(vp2 + 4);
        #pragma unroll
        for (int mt = 0; mt < 2; ++mt) {
            const float* xp = x + (size_t)(base + mt * 16 + r) * IN_F + ks * 32 + g * 8;
            f32x4 x0 = *(const f32x4*)(xp);
            f32x4 x1 = *(const f32x4*)(xp + 4);
            #pragma unroll
            for (int j = 0; j < 4; ++j) {
                p1[mt] += x0[j] * v10[j] + x1[j] * v11[j];
                p2[mt] += x0[j] * v20[j] + x1[j] * v21[j];
            }
            short8 af;
            af[0] = (short)f2bf(x0[0]); af[1] = (short)f2bf(x0[1]);
            af[2] = (short)f2bf(x0[2]); af[3] = (short)f2bf(x0[3]);
            af[4] = (short)f2bf(x1[0]); af[5] = (short)f2bf(x1[1]);
            af[6] = (short)f2bf(x1[2]); af[7] = (short)f2bf(x1[3]);
            #pragma unroll
            for (int ft = 0; ft < 4; ++ft)
                acc[mt][ft] = __builtin_amdgcn_mfma_f32_16x16x32_bf16(af, bf[ft], acc[mt][ft], 0, 0, 0);
        }
    }
    // C/D layout (HW-verified): col = lane&15 -> feature ft*16+r; row = g*4+reg -> node mt*16+g*4+reg

    // a1/a2: reduce partial dots over the 4 k-groups (lanes differing only in g)
    #pragma unroll
    for (int mt = 0; mt < 2; ++mt) {
        p1[mt] += __shfl_xor(p1[mt], 16, 64);
        p1[mt] += __shfl_xor(p1[mt], 32, 64);
        p2[mt] += __shfl_xor(p2[mt], 16, 64);
        p2[mt] += __shfl_xor(p2[mt], 32, 64);
    }
    if (lane < 16) {
        float b1 = a1bp[0], b2 = a2bp[0];
        #pragma unroll
        for (int mt = 0; mt < 2; ++mt) {
            a1[base + mt * 16 + lane] = p1[mt] + b1;
            a2[base + mt * 16 + lane] = p2[mt] + b2;
        }
    }

    // feat -> bf16, bounce through LDS so the global store is fully coalesced
    #pragma unroll
    for (int mt = 0; mt < 2; ++mt)
        #pragma unroll
        for (int ft = 0; ft < 4; ++ft)
            #pragma unroll
            for (int reg = 0; reg < 4; ++reg)
                lds[wid][mt * 16 + g * 4 + reg][ft * 16 + r] = f2bf(acc[mt][ft][reg]);
    // same-wave LDS RAW: compiler inserts lgkmcnt wait; tile is wave-private (no barrier)
    const char* lsrc = (const char*)(&lds[wid][0][0]);
    char* gdst = (char*)featb + (size_t)base * (OUT_F * 2);
    #pragma unroll
    for (int t = 0; t < 4; ++t) {
        i32x4 v = *(const i32x4*)(lsrc + t * 1024 + lane * 16);
        *(i32x4*)(gdst + t * 1024 + lane * 16) = v;
    }
}

// Kernel 2: per-node scores + gather-aggregate. One wave = 4 nodes x 16 lanes.
// Lane (q = lane>>4, e0 = lane&15): e0 = edge slot for scores, feature-quad for gathers.
// Edges processed in 2 batches of 8 with all 8 gathers issued before any consumption
// (keeps VGPR <= 64 for 8 waves/SIMD while holding 8 loads in flight per lane).
__global__ __launch_bounds__(256) void gat_agg_kernel(
    const int* __restrict__ dst, const unsigned short* __restrict__ featb,
    const float* __restrict__ a1, const float* __restrict__ a2,
    const float* __restrict__ bias, float* __restrict__ out)
{
    const int wid  = threadIdx.x >> 6;
    const int lane = threadIdx.x & 63;
    const int q  = lane >> 4;
    const int e0 = lane & 15;
    const int i = (blockIdx.x * 4 + wid) * 4 + q;   // N % 16 == 0: grid exact
    const int sb = lane & 48;                       // first lane of this node's group

    const int d = dst[i * DEG + e0];
    const float z = a1[i] + a2[d];
    const float s = __expf(fmaxf(z, ALPHA * z));    // leaky_relu == max(z, 0.2z)

    float se[16];
    float acc0 = 0.f, acc1 = 0.f, acc2 = 0.f, acc3 = 0.f;

    // ---- batch 1: edges 0..7 ----
    int de[8];
    #pragma unroll
    for (int e = 0; e < 8; ++e) de[e] = __shfl(d, sb + e, 64);
    u32x2 u[8];
    #pragma unroll
    for (int e = 0; e < 8; ++e)
        u[e] = *(const u32x2*)(featb + ((size_t)de[e] * OUT_F + e0 * 4));
    // collect scores + ssum while the gathers are in flight
    #pragma unroll
    for (int e = 0; e < 16; ++e) se[e] = __shfl(s, sb + e, 64);
    float ssum = 0.f;
    #pragma unroll
    for (int e = 0; e < 16; ++e) ssum += se[e];
    #pragma unroll
    for (int e = 0; e < 8; ++e) {
        acc0 += se[e] * __uint_as_float(u[e][0] << 16);
        acc1 += se[e] * __uint_as_float(u[e][0] & 0xffff0000u);
        acc2 += se[e] * __uint_as_float(u[e][1] << 16);
        acc3 += se[e] * __uint_as_float(u[e][1] & 0xffff0000u);
    }

    // ---- batch 2: edges 8..15 ----
    #pragma unroll
    for (int e = 0; e < 8; ++e) de[e] = __shfl(d, sb + 8 + e, 64);
    #pragma unroll
    for (int e = 0; e < 8; ++e)
        u[e] = *(const u32x2*)(featb + ((size_t)de[e] * OUT_F + e0 * 4));
    #pragma unroll
    for (int e = 0; e < 8; ++e) {
        acc0 += se[8 + e] * __uint_as_float(u[e][0] << 16);
        acc1 += se[8 + e] * __uint_as_float(u[e][0] & 0xffff0000u);
        acc2 += se[8 + e] * __uint_as_float(u[e][1] << 16);
        acc3 += se[8 + e] * __uint_as_float(u[e][1] & 0xffff0000u);
    }

    const float inv = 1.0f / ssum;
    const f32x4 bv = *(const f32x4*)(bias + e0 * 4);
    f32x4 o;
    o[0] = acc0 * inv + bv[0];
    o[1] = acc1 * inv + bv[1];
    o[2] = acc2 * inv + bv[2];
    o[3] = acc3 * inv + bv[3];
    *(f32x4*)(out + (size_t)i * OUT_F + e0 * 4) = o;
}

extern "C" void kernel_launch(void* const* d_in, const int* in_sizes, int n_in,
                              void* d_out, int out_size, void* d_ws, size_t ws_size,
                              hipStream_t stream) {
    (void)in_sizes; (void)n_in; (void)out_size; (void)ws_size;
    const float* x    = (const float*)d_in[0];
    const int*   edges= (const int*)d_in[1];   // [2, E] int32, row0=src, row1=dst
    const float* w    = (const float*)d_in[2];
    const float* a1w  = (const float*)d_in[3];
    const float* a1b  = (const float*)d_in[4];
    const float* a2w  = (const float*)d_in[5];
    const float* a2b  = (const float*)d_in[6];
    const float* bias = (const float*)d_in[7];
    float* out = (float*)d_out;

    // ws layout (all 16B-aligned): featb | a1 | a2 | v1 | v2 | wb
    unsigned short* featb = (unsigned short*)d_ws;                       // N*64 bf16 = 12.8 MB
    float* a1 = (float*)((char*)d_ws + (size_t)N_NODES * OUT_F * 2);
    float* a2 = a1 + N_NODES;
    float* v1 = a2 + N_NODES;
    float* v2 = v1 + IN_F;
    unsigned short* wb = (unsigned short*)(v2 + IN_F);

    const int* dst = edges + (size_t)N_NODES * DEG; // edges[1]

    prep_kernel<<<dim3((OUT_F * IN_F + 255) / 256), dim3(256), 0, stream>>>(
        w, a1w, a2w, wb, v1, v2);
    gat_feat_kernel<<<dim3((N_NODES + 127) / 128), dim3(256), 0, stream>>>(
        x, wb, v1, v2, a1b, a2b, featb, a1, a2);
    gat_agg_kernel<<<dim3((N_NODES + 15) / 16), dim3(256), 0, stream>>>(
        dst, featb, a1, a2, bias, out);
}